// Round 6
// baseline (543.753 us; speedup 1.0000x reference)
//
#include <hip/hip_runtime.h>
#include <hip/hip_bf16.h>
#include <math.h>

// Problem constants
constexpr int B_   = 2048;
constexpr int L_   = 64;
constexpr int V_   = 50000;
constexpr int IN_  = 300;
constexpr int M_   = 150;
constexpr int HID_ = 50;
constexpr int NC_  = 5;

// Padded dims
constexpr int KP_  = 160;            // global state row stride (bf16)
constexpr int CS_  = 152;            // in-block CinS stride (bf16)
constexpr int GN_  = 608;            // gate-interleaved N: col = 4m+g
constexpr int GNT_ = 19;             // N-tiles per wave-half (38 total)
constexpr int GKC_ = 5;              // K chunks of 32 (150 -> 160)
constexpr int GCH_ = GN_ * 32;       // shorts per B chunk (19456)
constexpr int GQS_ = GN_ * 8;        // shorts per quad segment (4864)
constexpr int LEAF_N  = 480;
constexpr int LEAF_NT = 15;
constexpr int LEAF_KC = 10;          // 300 -> 320
constexpr int LEAF_CH = LEAF_N * 32; // 15360
constexpr int LEAF_QS = LEAF_N * 8;  // 3840

typedef float f32x4  __attribute__((ext_vector_type(4)));
typedef short bf16x8 __attribute__((ext_vector_type(8)));
typedef short short4v __attribute__((ext_vector_type(4)));

__device__ __forceinline__ float rcp_f(float x) { return __builtin_amdgcn_rcpf(x); }
__device__ __forceinline__ float sgm(float x)   { return rcp_f(1.0f + __expf(-x)); }
__device__ __forceinline__ float tanh_f(float x){ return 1.0f - 2.0f * rcp_f(1.0f + __expf(2.0f * x)); }

__device__ __forceinline__ short f2bs(float f) {
    union { __hip_bfloat16 h; short s; } u; u.h = __float2bfloat16(f); return u.s;
}
__device__ __forceinline__ float bs2f(short s) {
    union { short s; __hip_bfloat16 h; } u; u.s = s; return __bfloat162float(u.h);
}

__device__ __forceinline__ void gl_lds16(const short* g, short* l) {
    __builtin_amdgcn_global_load_lds(
        (const __attribute__((address_space(1))) unsigned int*)g,
        (__attribute__((address_space(3))) unsigned int*)l, 16, 0, 0);
}

// ---------------------------------------------------------------------------
// K0: weight packing.
// Bg[kc][q][n'][8]: gate-interleaved level weights. k = kc*32+q*8+j;
//   n' = 4m+g: g<3 -> Wiouh[k][g*150+m], g==3 -> Wfh[k][m]; pad -> 0.
// Bx[kc][q][n][8]: leaf weights (plain n).
// ---------------------------------------------------------------------------
__global__ __launch_bounds__(256) void prep_kernel(
    const float* __restrict__ Wioux, const float* __restrict__ Wiouh,
    const float* __restrict__ Wfh, short* __restrict__ Bg, short* __restrict__ Bx)
{
    const int tid = blockIdx.x * blockDim.x + threadIdx.x;
    const int nthr = gridDim.x * blockDim.x;
    const int tot1 = GKC_ * GCH_;
    for (int idx = tid; idx < tot1; idx += nthr) {
        const int kc = idx / GCH_;
        int rem = idx % GCH_;
        const int q = rem / GQS_; rem %= GQS_;
        const int n = rem / 8, j = rem % 8;
        const int k = kc * 32 + q * 8 + j;
        const int m = n >> 2, g = n & 3;
        float v = 0.0f;
        if (k < M_ && m < M_)
            v = (g < 3) ? Wiouh[k * 450 + g * 150 + m] : Wfh[k * M_ + m];
        Bg[idx] = f2bs(v);
    }
    const int tot2 = LEAF_KC * LEAF_CH;
    for (int idx = tid; idx < tot2; idx += nthr) {
        const int kc = idx / LEAF_CH;
        int rem = idx % LEAF_CH;
        const int q = rem / LEAF_QS; rem %= LEAF_QS;
        const int n = rem / 8, j = rem % 8;
        const int k = kc * 32 + q * 8 + j;
        float v = (k < IN_ && n < 450) ? Wioux[k * 450 + n] : 0.0f;
        Bx[idx] = f2bs(v);
    }
}

// ---------------------------------------------------------------------------
// K1 (fused R6): emb -> GEMM1(Wioux,K=320) -> leaf h,c in LDS
//               -> GEMM2(Bg,K=160) -> LeafE[v][4m+g] (G | FC) to global.
// LeafH/LeafC never touch HBM. LDS = 81248 B -> 2 blocks/CU.
// ---------------------------------------------------------------------------
__global__ __launch_bounds__(512) void leafE_gemm(
    const float* __restrict__ emb, const short* __restrict__ Bx,
    const short* __restrict__ Bg,
    const float* __restrict__ bioux, const float* __restrict__ biouh,
    const float* __restrict__ bfh, short* __restrict__ LeafE)
{
    __shared__ __align__(16) char smem[81248];
    short* Bs     = (short*)smem;              // 38912 B: chunks / Es / Os
    short* AsF    = (short*)(smem + 38912);    // 20480 B: leaf h in A-frag layout
    short* As     = AsF;                       // first 4096 B during GEMM1
    short* CinS   = (short*)(smem + 59392);    // 19456 B: leaf c, stride 152
    float* bias_s = (float*)(smem + 78848);    // 2400 B: [0,450)=bioux+biouh, [450,600)=bfh
    float* Es     = (float*)smem;
    short* Os     = Bs;

    const int t = threadIdx.x;
    const int v0 = blockIdx.x * 64;
    const int w = t >> 6, lane = t & 63;
    const int mt = w & 3;
    const int lr = lane & 15, quad = lane >> 4;

    if (t < 600) bias_s[t] = (t < 450) ? (bioux[t] + biouh[t]) : bfh[t - 450];

    // ---------------- GEMM1: emb @ Wioux, N=480, K=320 ----------------
    const int nt1 = (w >> 2) * LEAF_NT;
    f32x4 acc[GNT_];
    #pragma unroll
    for (int i = 0; i < LEAF_NT; i++) { acc[i][0] = 0; acc[i][1] = 0; acc[i][2] = 0; acc[i][3] = 0; }

    const int arow = t >> 3, apart = t & 7;
    const int av = v0 + arow;
    const int aq = apart >> 1, aj = (apart & 1) * 4;

    for (int kc = 0; kc < LEAF_KC; kc++) {
        const short* bsrc = Bx + (size_t)kc * LEAF_CH;
        #pragma unroll
        for (int i = 0; i < 3; i++)
            gl_lds16(bsrc + (i * 512 + t) * 8, Bs + (i * 512 + (t & ~63)) * 8);
        if (t < 384)
            gl_lds16(bsrc + (1536 + t) * 8, Bs + (1536 + (t & ~63)) * 8);
        {
            const int k0 = kc * 32 + apart * 4;
            float4 x = make_float4(0.f, 0.f, 0.f, 0.f);
            if (av < V_ && k0 < IN_) x = *(const float4*)&emb[(size_t)av * IN_ + k0];
            short4v s;
            s[0] = f2bs(x.x); s[1] = f2bs(x.y); s[2] = f2bs(x.z); s[3] = f2bs(x.w);
            *(short4v*)&As[aq * 512 + arow * 8 + aj] = s;
        }
        __syncthreads();
        bf16x8 a = *(const bf16x8*)&As[quad * 512 + (mt * 16 + lr) * 8];
        #pragma unroll
        for (int i = 0; i < LEAF_NT; i++) {
            bf16x8 b = *(const bf16x8*)&Bs[quad * LEAF_QS + ((nt1 + i) * 16 + lr) * 8];
            acc[i] = __builtin_amdgcn_mfma_f32_16x16x32_bf16(a, b, acc[i], 0, 0, 0);
        }
        __syncthreads();
    }

    // ---- epilogue1: Es staging -> leaf h into AsF (A-frag layout), c into CinS
    for (int mc = 0; mc < 4; mc++) {
        if (mt == mc) {
            #pragma unroll
            for (int i = 0; i < LEAF_NT; i++) {
                const int col = (nt1 + i) * 16 + lr;
                #pragma unroll
                for (int r = 0; r < 4; r++) Es[(quad * 4 + r) * LEAF_N + col] = acc[i][r];
            }
        }
        __syncthreads();
        for (int p = t; p < 640; p += 512) {
            const int rl = p / 40, Q = p % 40;
            const int m0 = 4 * Q;
            short4v hq = {0, 0, 0, 0}, cq = {0, 0, 0, 0};
            if (Q < 38) {
                #pragma unroll
                for (int jj = 0; jj < 4; jj++) {
                    const int m = m0 + jj;
                    if (m < M_) {
                        const float i_ = Es[rl * LEAF_N + m]       + bias_s[m];
                        const float o_ = Es[rl * LEAF_N + m + 150] + bias_s[m + 150];
                        const float u_ = Es[rl * LEAF_N + m + 300] + bias_s[m + 300];
                        const float c = sgm(i_) * tanh_f(u_);
                        const float h = sgm(o_) * tanh_f(c);
                        hq[jj] = f2bs(h); cq[jj] = f2bs(c);
                    }
                }
            }
            const int row = mc * 16 + rl;
            const int kc = m0 >> 5, q = (m0 >> 3) & 3, j0 = m0 & 7;
            *(short4v*)&AsF[(kc * 4 + q) * 512 + row * 8 + j0] = hq;
            if (m0 < M_) *(short4v*)&CinS[row * CS_ + m0] = cq;
        }
        __syncthreads();
    }

    // ---------------- GEMM2: LeafH @ [Wiouh|Wfh], N=608, K=160 ----------------
    const int nt2 = (w >> 2) * GNT_;
    #pragma unroll
    for (int i = 0; i < GNT_; i++) { acc[i][0] = 0; acc[i][1] = 0; acc[i][2] = 0; acc[i][3] = 0; }

    for (int kc = 0; kc < GKC_; kc++) {
        const short* bsrc = Bg + (size_t)kc * GCH_;
        #pragma unroll
        for (int i = 0; i < 4; i++)
            gl_lds16(bsrc + (i * 512 + t) * 8, Bs + (i * 512 + (t & ~63)) * 8);
        if (t < 384)
            gl_lds16(bsrc + (2048 + t) * 8, Bs + (2048 + (t & ~63)) * 8);
        __syncthreads();
        bf16x8 a = *(const bf16x8*)&AsF[kc * 2048 + quad * 512 + (mt * 16 + lr) * 8];
        #pragma unroll
        for (int i = 0; i < GNT_; i++) {
            bf16x8 b = *(const bf16x8*)&Bs[quad * GQS_ + ((nt2 + i) * 16 + lr) * 8];
            acc[i] = __builtin_amdgcn_mfma_f32_16x16x32_bf16(a, b, acc[i], 0, 0, 0);
        }
        __syncthreads();
    }

    // ---- epilogue2: two 32-row phases -> Os -> coalesced LeafE store
    const int c = lane & 15;
    for (int ph = 0; ph < 2; ph++) {
        if ((mt >> 1) == ph) {
            const int rbase = 16 * (mt & 1) + 4 * quad;
            #pragma unroll
            for (int i = 0; i < GNT_; i++) {
                const int col = (nt2 + i) * 16 + c;
                const int m = col >> 2, g = col & 3;
                #pragma unroll
                for (int r = 0; r < 4; r++) {
                    short ov;
                    if (g == 3) {
                        if (m < M_) {
                            const float cc = bs2f(CinS[(32 * ph + rbase + r) * CS_ + m]);
                            ov = f2bs(sgm(acc[i][r] + bias_s[450 + m]) * cc);
                        } else ov = 0;
                    } else ov = f2bs(acc[i][r]);
                    Os[(rbase + r) * GN_ + col] = ov;
                }
            }
        }
        __syncthreads();
        const int vb = v0 + 32 * ph;
        const int4* os4 = (const int4*)Os;
        for (int u = t; u < 2432; u += 512) {
            const int row = u / 76;
            if (vb + row < V_)
                ((int4*)(LeafE + (size_t)(vb + row) * GN_))[u - row * 76] = os4[u];
        }
        __syncthreads();
    }
}

// ---------------------------------------------------------------------------
// Shared in-register LSTM epilogue for level GEMMs (gate-interleaved C).
// ---------------------------------------------------------------------------
__device__ __forceinline__ void level_epilogue(
    const f32x4* acc, int mt, int nt0, int lane,
    const short* CinS, int cstride, const float* bias_s, short* Hs, short* Cs)
{
    const int q = lane >> 4, c = lane & 15, g = c & 3, lb = lane & ~3;
    #pragma unroll
    for (int i = 0; i < GNT_; i++) {
        const int col = (nt0 + i) * 16 + c;
        const int m = col >> 2;
        const float vA = acc[i][0] + acc[i][1];
        const float vB = acc[i][2] + acc[i][3];
        const float iA = __shfl(vA, lb), oA = __shfl(vA, lb + 1), uA = __shfl(vA, lb + 2);
        const float iB = __shfl(vB, lb), oB = __shfl(vB, lb + 1), uB = __shfl(vB, lb + 2);
        const float fA0 = __shfl(acc[i][0], lb + 3), fA1 = __shfl(acc[i][1], lb + 3);
        const float fB0 = __shfl(acc[i][2], lb + 3), fB1 = __shfl(acc[i][3], lb + 3);
        if (g < 2 && m < M_) {
            const float iv = g ? iB : iA, ov = g ? oB : oA, uv = g ? uB : uA;
            const float fl = g ? fB0 : fA0, fr = g ? fB1 : fA1;
            const int node = 8 * mt + 2 * q + g;
            const int ch = 16 * mt + 4 * q + 2 * g;
            const float cl = bs2f(CinS[ch * cstride + m]);
            const float cr = bs2f(CinS[(ch + 1) * cstride + m]);
            const float bf = bias_s[450 + m];
            const float cv = sgm(iv + bias_s[m]) * tanh_f(uv + bias_s[m + 300])
                           + sgm(fl + bf) * cl + sgm(fr + bf) * cr;
            const float hv = sgm(ov + bias_s[m + 150]) * tanh_f(cv);
            Hs[node * KP_ + m] = f2bs(hv);
            Cs[node * KP_ + m] = f2bs(cv);
        }
    }
}

// ---------------------------------------------------------------------------
// K3: level 1 with fused level-0 gather. LDS 81248 B -> 2 blocks/CU.
// ---------------------------------------------------------------------------
__global__ __launch_bounds__(512) void level1_fused(
    const int* __restrict__ ltok, const int* __restrict__ rtok,
    const short* __restrict__ LeafE, const short* __restrict__ Bg,
    const float* __restrict__ biouh, const float* __restrict__ bfh,
    short* __restrict__ Hout, short* __restrict__ Cout)
{
    __shared__ __align__(16) char smem[81248];
    short* Bs     = (short*)smem;              // 38912 B (chunks / Hs+Cs out-stage)
    short* AsF    = (short*)(smem + 38912);    // 20480 B: level-0 h, A-frag layout
    short* CinS   = (short*)(smem + 59392);    // 19456 B: level-0 c, stride 152
    float* bias_s = (float*)(smem + 78848);    // 2400 B
    short* Hs = Bs;
    short* Cs = Bs + 32 * KP_;

    const int t = threadIdx.x;
    const int out0 = blockIdx.x * 32;
    const int w = t >> 6, lane = t & 63;
    const int mt = w & 3, nt0 = (w >> 2) * GNT_;
    const int lr = lane & 15, quad = lane >> 4;

    // prefetch Bg chunk 0 into Bs (Bs idle during level-0 phase)
    {
        const short* bsrc = Bg;
        #pragma unroll
        for (int i = 0; i < 4; i++)
            gl_lds16(bsrc + (i * 512 + t) * 8, Bs + (i * 512 + (t & ~63)) * 8);
        if (t < 384)
            gl_lds16(bsrc + (2048 + t) * 8, Bs + (2048 + (t & ~63)) * 8);
    }
    if (t < 600) bias_s[t] = (t < 450) ? biouh[t] : bfh[t - 450];
    __syncthreads();

    // ---- fused level-0: 64 node h/c rows into AsF / CinS ----
    {
        const int row = t >> 3, qs = t & 7;
        const int half = B_ * L_;
        const int gidx = blockIdx.x * 128 + 2 * row;
        const int tl = (gidx < half) ? ltok[gidx] : rtok[gidx - half];
        const int tr = (gidx + 1 < half) ? ltok[gidx + 1] : rtok[gidx + 1 - half];
        const short* el = LeafE + (size_t)tl * GN_;
        const short* er = LeafE + (size_t)tr * GN_;
        #pragma unroll
        for (int s = 0; s < 5; s++) {
            const int Q = qs + 8 * s;          // m-quad 0..39
            short4v hq = {0, 0, 0, 0}, cq = {0, 0, 0, 0};
            if (Q < 38) {
                union { int4 v[2]; short s16[16]; } ue, ur;
                ue.v[0] = *(const int4*)(el + Q * 16);
                ue.v[1] = *(const int4*)(el + Q * 16 + 8);
                ur.v[0] = *(const int4*)(er + Q * 16);
                ur.v[1] = *(const int4*)(er + Q * 16 + 8);
                #pragma unroll
                for (int jj = 0; jj < 4; jj++) {
                    const int m = 4 * Q + jj;
                    if (m < M_) {
                        const float i_ = bs2f(ue.s16[4 * jj])     + bs2f(ur.s16[4 * jj])     + bias_s[m];
                        const float o_ = bs2f(ue.s16[4 * jj + 1]) + bs2f(ur.s16[4 * jj + 1]) + bias_s[m + 150];
                        const float u_ = bs2f(ue.s16[4 * jj + 2]) + bs2f(ur.s16[4 * jj + 2]) + bias_s[m + 300];
                        const float fc = bs2f(ue.s16[4 * jj + 3]) + bs2f(ur.s16[4 * jj + 3]);
                        const float cv = sgm(i_) * tanh_f(u_) + fc;
                        const float hv = sgm(o_) * tanh_f(cv);
                        hq[jj] = f2bs(hv); cq[jj] = f2bs(cv);
                    }
                }
            }
            const int m0 = 4 * Q;
            const int kc = m0 >> 5, q = (m0 >> 3) & 3, j0 = m0 & 7;
            *(short4v*)&AsF[(kc * 4 + q) * 512 + row * 8 + j0] = hq;
            if (m0 < M_) *(short4v*)&CinS[row * CS_ + m0] = cq;
        }
    }

    f32x4 acc[GNT_];
    #pragma unroll
    for (int i = 0; i < GNT_; i++) { acc[i][0] = 0; acc[i][1] = 0; acc[i][2] = 0; acc[i][3] = 0; }

    for (int kc = 0; kc < GKC_; kc++) {
        if (kc > 0) {
            const short* bsrc = Bg + (size_t)kc * GCH_;
            #pragma unroll
            for (int i = 0; i < 4; i++)
                gl_lds16(bsrc + (i * 512 + t) * 8, Bs + (i * 512 + (t & ~63)) * 8);
            if (t < 384)
                gl_lds16(bsrc + (2048 + t) * 8, Bs + (2048 + (t & ~63)) * 8);
        }
        __syncthreads();
        bf16x8 a = *(const bf16x8*)&AsF[kc * 2048 + quad * 512 + (mt * 16 + lr) * 8];
        #pragma unroll
        for (int i = 0; i < GNT_; i++) {
            bf16x8 b = *(const bf16x8*)&Bs[quad * GQS_ + ((nt0 + i) * 16 + lr) * 8];
            acc[i] = __builtin_amdgcn_mfma_f32_16x16x32_bf16(a, b, acc[i], 0, 0, 0);
        }
        __syncthreads();
    }

    if (t < 320) { const int node = t / 10, mm = 150 + t % 10;
                   Hs[node * KP_ + mm] = 0; Cs[node * KP_ + mm] = 0; }
    level_epilogue(acc, mt, nt0, lane, CinS, CS_, bias_s, Hs, Cs);
    __syncthreads();
    int4* Hg = (int4*)(Hout + (size_t)out0 * KP_);
    int4* Cg = (int4*)(Cout + (size_t)out0 * KP_);
    const int4* hs4 = (const int4*)Hs;
    const int4* cs4 = (const int4*)Cs;
    for (int u = t; u < 1280; u += 512) {
        if (u < 640) Hg[u] = hs4[u]; else Cg[u - 640] = cs4[u - 640];
    }
}

// ---------------------------------------------------------------------------
// K4: internal levels 2..5 (A and Cin from global state buffers).
// ---------------------------------------------------------------------------
__global__ __launch_bounds__(512) void level_gemm(
    const short* __restrict__ Hin, const short* __restrict__ Cin,
    const short* __restrict__ Bg,
    const float* __restrict__ biouh, const float* __restrict__ bfh,
    short* __restrict__ Hout, short* __restrict__ Cout)
{
    __shared__ __align__(16) char smem[GCH_ * 2 + 4096 + 20480 + 2400];
    short* Bs     = (short*)smem;
    short* As     = (short*)(smem + GCH_ * 2);
    short* CinS   = (short*)(smem + GCH_ * 2 + 4096);
    float* bias_s = (float*)(smem + GCH_ * 2 + 4096 + 20480);
    short* Hs = Bs;
    short* Cs = Bs + 32 * KP_;

    const int t = threadIdx.x;
    const int row0 = blockIdx.x * 64, out0 = blockIdx.x * 32;
    const int w = t >> 6, lane = t & 63;
    const int mt = w & 3, nt0 = (w >> 2) * GNT_;
    const int lr = lane & 15, quad = lane >> 4;

    if (t < 600) bias_s[t] = (t < 450) ? biouh[t] : bfh[t - 450];
    // CinS: 10240 shorts = 1280 lane-loads (2 full rounds + t<256 tail)
    const short* csrc = Cin + (size_t)row0 * KP_;
    #pragma unroll
    for (int i = 0; i < 2; i++)
        gl_lds16(csrc + (i * 512 + t) * 8, CinS + (i * 512 + (t & ~63)) * 8);
    if (t < 256)
        gl_lds16(csrc + (1024 + t) * 8, CinS + (1024 + (t & ~63)) * 8);

    f32x4 acc[GNT_];
    #pragma unroll
    for (int i = 0; i < GNT_; i++) { acc[i][0] = 0; acc[i][1] = 0; acc[i][2] = 0; acc[i][3] = 0; }

    const short* asrc = Hin + (size_t)(row0 + (t & 63)) * KP_ + (t >> 6) * 8;

    for (int kc = 0; kc < GKC_; kc++) {
        const short* bsrc = Bg + (size_t)kc * GCH_;
        #pragma unroll
        for (int i = 0; i < 4; i++)
            gl_lds16(bsrc + (i * 512 + t) * 8, Bs + (i * 512 + (t & ~63)) * 8);
        if (t < 384)
            gl_lds16(bsrc + (2048 + t) * 8, Bs + (2048 + (t & ~63)) * 8);
        if (t < 256)
            gl_lds16(asrc + kc * 32, As + (t & ~63) * 8);
        __syncthreads();
        bf16x8 a = *(const bf16x8*)&As[quad * 512 + (mt * 16 + lr) * 8];
        #pragma unroll
        for (int i = 0; i < GNT_; i++) {
            bf16x8 b = *(const bf16x8*)&Bs[quad * GQS_ + ((nt0 + i) * 16 + lr) * 8];
            acc[i] = __builtin_amdgcn_mfma_f32_16x16x32_bf16(a, b, acc[i], 0, 0, 0);
        }
        __syncthreads();
    }

    if (t < 320) { const int node = t / 10, mm = 150 + t % 10;
                   Hs[node * KP_ + mm] = 0; Cs[node * KP_ + mm] = 0; }
    level_epilogue(acc, mt, nt0, lane, CinS, KP_, bias_s, Hs, Cs);
    __syncthreads();
    int4* Hg = (int4*)(Hout + (size_t)out0 * KP_);
    int4* Cg = (int4*)(Cout + (size_t)out0 * KP_);
    const int4* hs4 = (const int4*)Hs;
    const int4* cs4 = (const int4*)Cs;
    for (int u = t; u < 1280; u += 512) {
        if (u < 640) Hg[u] = hs4[u]; else Cg[u - 640] = cs4[u - 640];
    }
}

// ---------------------------------------------------------------------------
// K5: similarity head (one wave per pair).
// ---------------------------------------------------------------------------
__global__ __launch_bounds__(64) void head_kernel(
    const short* __restrict__ RootH,
    const float* __restrict__ Wh, const float* __restrict__ bh,
    const float* __restrict__ Wp, const float* __restrict__ bp,
    float* __restrict__ out)
{
    __shared__ float vec[2 * M_];
    __shared__ float mid[HID_];
    __shared__ float lg[NC_];
    __shared__ float lse;

    const int b = blockIdx.x;
    const int t = threadIdx.x;
    const short* lh = RootH + (size_t)b * KP_;
    const short* rh = RootH + (size_t)(B_ + b) * KP_;

    for (int i = t; i < M_; i += 64) {
        const float a = bs2f(lh[i]), c = bs2f(rh[i]);
        vec[i]      = a * c;
        vec[M_ + i] = fabsf(a - c);
    }
    __syncthreads();

    for (int j = t; j < HID_; j += 64) {
        float acc = bh[j];
        for (int k = 0; k < 2 * M_; k++) acc += vec[k] * Wh[k * HID_ + j];
        mid[j] = sgm(acc);
    }
    __syncthreads();

    if (t < NC_) {
        float acc = bp[t];
        for (int k = 0; k < HID_; k++) acc += mid[k] * Wp[k * NC_ + t];
        lg[t] = acc;
    }
    __syncthreads();

    if (t == 0) {
        float mx = lg[0];
        for (int i = 1; i < NC_; i++) mx = fmaxf(mx, lg[i]);
        float s = 0.0f;
        for (int i = 0; i < NC_; i++) s += expf(lg[i] - mx);
        lse = mx + logf(s);
    }
    __syncthreads();

    if (t < NC_) out[b * NC_ + t] = lg[t] - lse;
}

// ---------------------------------------------------------------------------
extern "C" void kernel_launch(void* const* d_in, const int* in_sizes, int n_in,
                              void* d_out, int out_size, void* d_ws, size_t ws_size,
                              hipStream_t stream)
{
    const int*   ltok  = (const int*)d_in[0];
    const int*   rtok  = (const int*)d_in[1];
    const float* emb   = (const float*)d_in[2];
    const float* Wioux = (const float*)d_in[3];
    const float* bioux = (const float*)d_in[4];
    const float* Wiouh = (const float*)d_in[5];
    const float* biouh = (const float*)d_in[6];
    const float* Wfh   = (const float*)d_in[9];
    const float* bfh   = (const float*)d_in[10];
    const float* Wh    = (const float*)d_in[11];
    const float* bh    = (const float*)d_in[12];
    const float* Wp    = (const float*)d_in[13];
    const float* bp    = (const float*)d_in[14];
    float* out = (float*)d_out;

    char* ws = (char*)d_ws;
    size_t off = 0;
    auto carve = [&](size_t bytes) { char* p = ws + off; off += (bytes + 255) & ~(size_t)255; return p; };
    short* Bg    = (short*)carve((size_t)GKC_ * GCH_ * 2);
    short* Bx    = (short*)carve((size_t)LEAF_KC * LEAF_CH * 2);
    short* LeafE = (short*)carve((size_t)V_ * GN_ * 2);      // 60.8 MB
    short* HA    = (short*)carve((size_t)65536 * KP_ * 2);   // 21 MB
    short* CA    = (short*)carve((size_t)65536 * KP_ * 2);   // 21 MB
    short* HB    = (short*)carve((size_t)32768 * KP_ * 2);   // 10.5 MB
    short* CB    = (short*)carve((size_t)32768 * KP_ * 2);   // 10.5 MB

    hipLaunchKernelGGL(prep_kernel, dim3(128), dim3(256), 0, stream, Wioux, Wiouh, Wfh, Bg, Bx);
    hipLaunchKernelGGL(leafE_gemm, dim3((V_ + 63) / 64), dim3(512), 0, stream,
                       emb, Bx, Bg, bioux, biouh, bfh, LeafE);
    // level 1 (fused level-0 gather): 131072 nodes -> 65536 rows
    hipLaunchKernelGGL(level1_fused, dim3(2048), dim3(512), 0, stream,
                       ltok, rtok, LeafE, Bg, biouh, bfh, HA, CA);
    // levels 2..5
    hipLaunchKernelGGL(level_gemm, dim3(1024), dim3(512), 0, stream,
                       HA, CA, Bg, biouh, bfh, HB, CB);
    hipLaunchKernelGGL(level_gemm, dim3(512), dim3(512), 0, stream,
                       HB, CB, Bg, biouh, bfh, HA, CA);
    hipLaunchKernelGGL(level_gemm, dim3(256), dim3(512), 0, stream,
                       HA, CA, Bg, biouh, bfh, HB, CB);
    hipLaunchKernelGGL(level_gemm, dim3(128), dim3(512), 0, stream,
                       HB, CB, Bg, biouh, bfh, HA, CA);
    hipLaunchKernelGGL(head_kernel, dim3(B_), dim3(64), 0, stream, HA, Wh, bh, Wp, bp, out);
}